// Round 8
// baseline (415.615 us; speedup 1.0000x reference)
//
#include <hip/hip_runtime.h>
#include <hip/hip_bf16.h>
#include <math.h>

// ---------- types ----------
typedef __attribute__((ext_vector_type(8))) short s8vec;     // 8 x bf16 bits (4 VGPRs)
typedef __attribute__((ext_vector_type(16))) float f32x16;   // 32x32 MFMA C/D
typedef __attribute__((ext_vector_type(4))) unsigned short us4;
typedef __attribute__((ext_vector_type(8))) unsigned short us8;

__device__ __forceinline__ unsigned short f2bf(float f) {
  unsigned u = __float_as_uint(f);
  u = (u + 0x7fffu + ((u >> 16) & 1u)) >> 16;   // RNE
  return (unsigned short)u;
}
__device__ __forceinline__ float bf2f(unsigned short u) {
  return __uint_as_float(((unsigned)u) << 16);
}

// fast gelu: t * sigmoid(1.5957691t + 0.07135481t^3); |err vs erf-gelu| < 3e-3
__device__ __forceinline__ float fast_gelu(float t) {
  float t2 = t * t;
  float u = t * (1.59576912f + 0.07135481f * t2);
  float e = __expf(-u);
  return t * __frcp_rn(1.0f + e);
}

// async global->LDS, 16B per lane. LDS dest = wave-uniform base + lane*16.
// offset param ALWAYS 0 (nonzero was round-7's prime NaN suspect).
__device__ __forceinline__ void async_ld16(const unsigned short* g, unsigned short* l) {
  __builtin_amdgcn_global_load_lds(
      (__attribute__((address_space(1))) void*)g,
      (__attribute__((address_space(3))) void*)l, 16, 0, 0);
}

#define SB0() __builtin_amdgcn_sched_barrier(0)

// ============================================================================
// gemm2b: 128x128 NT GEMM, 8 waves, 64 KiB LDS -> 2 BLOCKS/CU = 4 waves/SIMD.
// THE OCCUPANCY DISCRIMINATOR, rebuilt from proven-only primitives:
//  - round-4 swizzle: 16B chunk c of row r at phys c ^ (r&7) ^ ((r>>3)&3);
//    global source pre-swizzled, LDS linear, offset-0 global_load_lds.
//  - round-4 fragment math: pc[s] = (((2s+fq)^swz)<<3), swz=(l&7)^((l>>3)&3).
//  - round-4 2-window schedule with counted lgkm/vmcnt.
// Wave tile 64x32: acc = 2 x f32x16 (32 VGPR); frags 12 x s8vec (48 VGPR);
// total ~110 <= 128 cap from __launch_bounds__(512, 4).
//
// Staging (512 thr, 8 KiB/issue = 64 rows): issue S_j of a tile covers rows
// j*32 + {0-31, 64-95}-pattern: rowbase(w) = (w&3)*8 + (w>>2)*64 + j*32;
// thread row = rowbase + (l>>3), chunk cS = (l&7) ^ (l>>3) ^ (w&3)
// (f(row) = (row&7)^((row>>3)&3) = (l>>3)^(w&3) since rowbase%8==0 and
// (rowbase>>3)&3 == w&3 for both j).  A:S0 = mf0 rows, A:S1 = mf1 rows;
// B rows are ALL read in window A (4 wn values cover 0..127).
//
// Per K-tile (buf bf = t&1):
//  WA: read b[4]+aA[4] (batch1, 8), read aC[4] (batch2, 4);
//      stage A_S1(t+1, OTHER buf)  [that region's last reader: tile t-1's
//      batch2, done at WB(t-1) lgkm(0), barrier after];
//      lgkm(4) [batch1 done, batch2 in flight; DS retires in-order];
//      setprio1; 4 MFMA (acc[0]); setprio0; barrier.
//  WB: stage B_S0,B_S1,A_S0 (t+2, THIS buf) [all read in batch1; every wave
//      passed lgkm(4) before the WA barrier];
//      lgkm(0); setprio1; 4 MFMA (acc[1]); setprio0;
//      vmcnt(3) (tail 0); barrier.
// vmcnt ledger (4 stage-issues/thread/tile): prologue t0 full (4) + t1 B+A_S0
// (3) -> vmcnt(3) drains t0.  Steady queue at WB(t) end: [t+1: 4][t+2: 3] ->
// vmcnt(3) drains all of t+1 (incl. A_S1 staged at WA(t)).  Tail: vmcnt(0).
// T1 XCD-aware bijective remap (nwg%8==0, gx/gy pow2 at all sites).
// C/D: col=lane&31, row=(reg&3)+8*(reg>>2)+4*(lane>>5).
// ============================================================================

#define GSTA(j, tk, bofs)                                                   \
  async_ld16(srcA0 + (size_t)(j) * 32 * K + ((size_t)(tk) << 6),            \
             &As[(bofs) + ldsS0 + (j) * 2048])
#define GSTB(j, tk, bofs)                                                   \
  async_ld16(srcB0 + (size_t)(j) * 32 * K + ((size_t)(tk) << 6),            \
             &Bs[(bofs) + ldsS0 + (j) * 2048])

template <int EPI>
__global__ __launch_bounds__(512, 4) void gemm2b(
    const unsigned short* __restrict__ A, const unsigned short* __restrict__ B,
    float* __restrict__ outF, unsigned short* __restrict__ outB,
    const float* __restrict__ bias, const float* __restrict__ res,
    int M, int N, int K,
    long long bA, long long bB, long long bO, long long bR, float scale)
{
  constexpr int TBUF = 128 * 64;   // 8192 elements = 16 KiB per buffer
  __shared__ __align__(16) unsigned short As[2 * TBUF];   // 32 KiB
  __shared__ __align__(16) unsigned short Bs[2 * TBUF];   // 32 KiB

  (void)M;
  const int tid = threadIdx.x;
  const int w = tid >> 6;          // wave 0..7
  const int l = tid & 63;

  // ---- T1: XCD-aware bijective remap (nwg % 8 == 0, gx/gy pow2) ----
  const unsigned gx = gridDim.x, gy = gridDim.y;
  unsigned lin = blockIdx.x + gx * (blockIdx.y + gy * blockIdx.z);
  const unsigned nwg = gx * gy * gridDim.z;
  lin = (lin & 7u) * (nwg >> 3) + (lin >> 3);
  const unsigned bx = lin & (gx - 1u);
  const unsigned tmp = lin >> __builtin_ctz(gx);
  const unsigned by = tmp & (gy - 1u);
  const unsigned bz = tmp >> __builtin_ctz(gy);

  const int z = (int)bz;
  A += (size_t)z * bA;
  B += (size_t)z * bB;
  const size_t tileM = (size_t)by * 128;
  const size_t tileN = (size_t)bx * 128;

  // ---- staging bases (global pre-swizzled, LDS linear) ----
  const int rowbase = (w & 3) * 8 + (w >> 2) * 64;        // S_j adds j*32
  const int cS = (l & 7) ^ (l >> 3) ^ (w & 3);            // invariant in j
  const unsigned short* srcA0 = A + (tileM + rowbase + (l >> 3)) * (size_t)K + (cS << 3);
  const unsigned short* srcB0 = B + (tileN + rowbase + (l >> 3)) * (size_t)K + (cS << 3);
  const int ldsS0 = rowbase * 64;                          // wave-uniform

  // ---- compute-side fragment addressing (round-4 verbatim) ----
  const int wm = w >> 2;           // wave M origin / 64 (0..1)
  const int wn = w & 3;            // wave N origin / 32 (0..3)
  const int fr = l & 31;
  const int fq = l >> 5;
  const int swz = (l & 7) ^ ((l >> 3) & 3);
  int pc[4];
#pragma unroll
  for (int s = 0; s < 4; ++s) pc[s] = ((((s << 1) + fq) ^ swz) << 3);
  const int aoff0 = (wm * 64 + fr) * 64;                   // mf0 rows
  const int aoff1 = (wm * 64 + 32 + fr) * 64;              // mf1 rows
  const int boff = (wn * 32 + fr) * 64;

  f32x16 acc[2] = {};
  const int NT = K >> 6;           // K-tiles (16 at both call sites)

  // ---- prologue: t0 full (4), t1 B+A_S0 (3); vmcnt(3) -> t0 resident ----
  GSTB(0, 0, 0); GSTB(1, 0, 0); GSTA(0, 0, 0); GSTA(1, 0, 0);
  GSTB(0, 1, TBUF); GSTB(1, 1, TBUF); GSTA(0, 1, TBUF);
  asm volatile("s_waitcnt vmcnt(3)" ::: "memory");
  __builtin_amdgcn_s_barrier();

  for (int t = 0; t < NT; ++t) {
    const int bf = t & 1;
    const int cb = bf * TBUF, ob = (bf ^ 1) * TBUF;
    const bool g1 = (t + 1 < NT), g2 = (t + 2 < NT);
    s8vec b[4], aA[4], aC[4];

    // -- WA: batch1 (B + A-mf0), batch2 (A-mf1); stage A_S1(t+1, other) --
#pragma unroll
    for (int s = 0; s < 4; ++s) {
      b[s]  = *(const s8vec*)&Bs[cb + boff + pc[s]];
      aA[s] = *(const s8vec*)&As[cb + aoff0 + pc[s]];
    }
    SB0();                         // pin batch boundary: (b,aA) | (aC)
#pragma unroll
    for (int s = 0; s < 4; ++s)
      aC[s] = *(const s8vec*)&As[cb + aoff1 + pc[s]];
    if (g1) GSTA(1, t + 1, ob);
    SB0();
    asm volatile("s_waitcnt lgkmcnt(4)" ::: "memory");   // batch1 done
    SB0();
    __builtin_amdgcn_s_setprio(1);
#pragma unroll
    for (int s = 0; s < 4; ++s)
      acc[0] = __builtin_amdgcn_mfma_f32_32x32x16_bf16(aA[s], b[s], acc[0], 0, 0, 0);
    SB0();
    __builtin_amdgcn_s_setprio(0);
    __builtin_amdgcn_s_barrier();   // all waves past lgkm(4): B/A_S0 restageable

    // -- WB: stage B_S0,B_S1,A_S0 (t+2, this buf); MFMA mf1; counted vmcnt --
    if (g2) { GSTB(0, t + 2, cb); GSTB(1, t + 2, cb); GSTA(0, t + 2, cb); }
    SB0();
    asm volatile("s_waitcnt lgkmcnt(0)" ::: "memory");   // batch2 done
    SB0();
    __builtin_amdgcn_s_setprio(1);
#pragma unroll
    for (int s = 0; s < 4; ++s)
      acc[1] = __builtin_amdgcn_mfma_f32_32x32x16_bf16(aC[s], b[s], acc[1], 0, 0, 0);
    SB0();
    __builtin_amdgcn_s_setprio(0);
    if (g2) asm volatile("s_waitcnt vmcnt(3)" ::: "memory");
    else    asm volatile("s_waitcnt vmcnt(0)" ::: "memory");
    __builtin_amdgcn_s_barrier();   // tile t+1 fully resident
  }

  // ---- epilogue.  C/D: col = lane&31, row = (reg&3)+8*(reg>>2)+4*(lane>>5) ----
  float* oF = outF + (size_t)z * bO;
  unsigned short* oB = outB + (size_t)z * bO;
  const float* rs = res + (size_t)z * bR;

  float bc = 0.f;
  if (EPI >= 2) bc = bias[tileN + wn * 32 + fr];

#pragma unroll
  for (int mf = 0; mf < 2; ++mf) {
#pragma unroll
    for (int r = 0; r < 16; ++r) {
      const size_t row = tileM + wm * 64 + (mf << 5) + (r & 3) + ((r >> 2) << 3) + (fq << 2);
      const size_t rb = row * (size_t)N;
      const size_t col = tileN + wn * 32 + fr;
      const float v = acc[mf][r];
      if (EPI == 0) {
        oB[rb + col] = f2bf(v * scale);
      } else if (EPI == 1) {
        oF[rb + col] = v + rs[rb + col];
      } else if (EPI == 2) {
        oB[rb + col] = f2bf(fast_gelu(v + bc));
      } else {
        oF[rb + col] = v + bc + rs[rb + col];
      }
    }
  }
}

// ============================================================================
// Round-4 256x128 NT GEMM (measured best for the N=1024 sites: PV, FFN2).
// ============================================================================

#define STA(q, tk, bofs)                                                    \
  async_ld16(srcA0 + (size_t)(q) * 32 * K + ((size_t)(tk) << 6),            \
             &As[(bofs) + ldsA0 + (q) * 2048])
#define STB(j, tk, bofs)                                                    \
  async_ld16(srcB0 + (size_t)(j) * 64 * K + ((size_t)(tk) << 6),            \
             &Bs[(bofs) + ldsB0 + (j) * 4096])

template <int BN, int EPI>
__global__ __launch_bounds__(512, 2) void gemm_nt8(
    const unsigned short* __restrict__ A, const unsigned short* __restrict__ B,
    float* __restrict__ outF, unsigned short* __restrict__ outB,
    const float* __restrict__ bias, const float* __restrict__ res,
    int M, int N, int K,
    long long bA, long long bB, long long bO, long long bR, float scale)
{
  static_assert(BN == 256 || BN == 128, "BN must be 256 or 128");
  constexpr int NB = BN / 64;
  constexpr int NF = BN / 128;
  constexpr int WN = BN / 4;
  constexpr int ABUF = 256 * 64;
  constexpr int BBUF = BN * 64;

  __shared__ __align__(16) unsigned short As[2 * ABUF];
  __shared__ __align__(16) unsigned short Bs[2 * BBUF];

  (void)M;
  const int tid = threadIdx.x;
  const int w = tid >> 6;
  const int l = tid & 63;

  const unsigned gx = gridDim.x, gy = gridDim.y;
  unsigned lin = blockIdx.x + gx * (blockIdx.y + gy * blockIdx.z);
  const unsigned nwg = gx * gy * gridDim.z;
  lin = (lin & 7u) * (nwg >> 3) + (lin >> 3);
  const unsigned bx = lin & (gx - 1u);
  const unsigned tmp = lin >> __builtin_ctz(gx);
  const unsigned by = tmp & (gy - 1u);
  const unsigned bz = tmp >> __builtin_ctz(gy);

  const int z = (int)bz;
  A += (size_t)z * bA;
  B += (size_t)z * bB;
  const size_t tileM = (size_t)by * 256;
  const size_t tileN = (size_t)bx * BN;

  const int sub = w & 3, half = w >> 2;
  const int rA = sub * 8 + half * 128 + (l >> 3);
  const int cA = (l & 7) ^ (rA & 7) ^ ((rA >> 3) & 3);
  const unsigned short* srcA0 = A + (tileM + rA) * (size_t)K + (cA << 3);
  const int ldsA0 = (sub * 8 + half * 128) * 64;

  const int rB = w * 8 + (l >> 3);
  const int cB = (l & 7) ^ (rB & 7) ^ ((rB >> 3) & 3);
  const unsigned short* srcB0 = B + (tileN + rB) * (size_t)K + (cB << 3);
  const int ldsB0 = (w * 8) * 64;

  const int wm = half;
  const int wn = sub;
  const int fr = l & 31;
  const int fq = l >> 5;
  const int swz = (l & 7) ^ ((l >> 3) & 3);
  int pc[4];
#pragma unroll
  for (int s = 0; s < 4; ++s) pc[s] = ((((s << 1) + fq) ^ swz) << 3);
  const int aoff = (wm * 128 + fr) * 64;
  int boff[NF];
#pragma unroll
  for (int nf = 0; nf < NF; ++nf) boff[nf] = (wn * WN + nf * 32 + fr) * 64;

  f32x16 acc[4][NF] = {};
  const int NT = K >> 6;

  STA(0, 0, 0); STA(1, 0, 0); STA(2, 0, 0); STA(3, 0, 0);
#pragma unroll
  for (int j = 0; j < NB; ++j) STB(j, 0, 0);
#pragma unroll
  for (int j = 0; j < NB; ++j) STB(j, 1, BBUF);
  STA(0, 1, ABUF); STA(1, 1, ABUF);
  if constexpr (NB == 4) asm volatile("s_waitcnt vmcnt(6)" ::: "memory");
  else                   asm volatile("s_waitcnt vmcnt(4)" ::: "memory");
  __builtin_amdgcn_s_barrier();

  auto tile = [&](int t, int bf) {
    const int aB = bf * ABUF, bBo = bf * BBUF, oaB = (bf ^ 1) * ABUF;
    const bool g1 = (t + 1 < NT), g2 = (t + 2 < NT);
    s8vec b[NF][4], aA[2][4], aC[2][4];

#pragma unroll
    for (int s = 0; s < 4; ++s) {
#pragma unroll
      for (int nf = 0; nf < NF; ++nf)
        b[nf][s] = *(const s8vec*)&Bs[bBo + boff[nf] + pc[s]];
      aA[0][s] = *(const s8vec*)&As[aB + aoff + 0 * 2048 + pc[s]];
      aA[1][s] = *(const s8vec*)&As[aB + aoff + 1 * 2048 + pc[s]];
    }
    SB0();
#pragma unroll
    for (int s = 0; s < 4; ++s) {
      aC[0][s] = *(const s8vec*)&As[aB + aoff + 2 * 2048 + pc[s]];
      aC[1][s] = *(const s8vec*)&As[aB + aoff + 3 * 2048 + pc[s]];
    }
    if (g1) { STA(2, t + 1, oaB); STA(3, t + 1, oaB); }
    SB0();
    asm volatile("s_waitcnt lgkmcnt(8)" ::: "memory");
    SB0();
    __builtin_amdgcn_s_setprio(1);
#pragma unroll
    for (int s = 0; s < 4; ++s)
#pragma unroll
      for (int i = 0; i < 2; ++i)
#pragma unroll
        for (int nf = 0; nf < NF; ++nf)
          acc[i][nf] = __builtin_amdgcn_mfma_f32_32x32x16_bf16(aA[i][s], b[nf][s], acc[i][nf], 0, 0, 0);
    SB0();
    __builtin_amdgcn_s_setprio(0);
    __builtin_amdgcn_s_barrier();

    if (g2) {
#pragma unroll
      for (int j = 0; j < NB; ++j) STB(j, t + 2, bBo);
      STA(0, t + 2, aB); STA(1, t + 2, aB);
    }
    SB0();
    asm volatile("s_waitcnt lgkmcnt(0)" ::: "memory");
    SB0();
    __builtin_amdgcn_s_setprio(1);
#pragma unroll
    for (int s = 0; s < 4; ++s)
#pragma unroll
      for (int i = 0; i < 2; ++i)
#pragma unroll
        for (int nf = 0; nf < NF; ++nf)
          acc[2 + i][nf] = __builtin_amdgcn_mfma_f32_32x32x16_bf16(aC[i][s], b[nf][s], acc[2 + i][nf], 0, 0, 0);
    SB0();
    __builtin_amdgcn_s_setprio(0);
    if (g2) {
      if constexpr (NB == 4) asm volatile("s_waitcnt vmcnt(6)" ::: "memory");
      else                   asm volatile("s_waitcnt vmcnt(4)" ::: "memory");
    } else {
      asm volatile("s_waitcnt vmcnt(0)" ::: "memory");
    }
    __builtin_amdgcn_s_barrier();
  };

  for (int t = 0; t < NT; t += 2) { tile(t, 0); tile(t + 1, 1); }

  float* oF = outF + (size_t)z * bO;
  unsigned short* oB = outB + (size_t)z * bO;
  const float* rs = res + (size_t)z * bR;

  float bcol[NF];
  if (EPI >= 2) {
#pragma unroll
    for (int nf = 0; nf < NF; ++nf) bcol[nf] = bias[tileN + wn * WN + nf * 32 + fr];
  }

#pragma unroll
  for (int mf = 0; mf < 4; ++mf) {
#pragma unroll
    for (int r = 0; r < 16; ++r) {
      const size_t row = tileM + wm * 128 + (mf << 5) + (r & 3) + ((r >> 2) << 3) + (fq << 2);
      const size_t rb = row * (size_t)N;
#pragma unroll
      for (int nf = 0; nf < NF; ++nf) {
        const size_t col = tileN + wn * WN + (nf << 5) + fr;
        const float v = acc[mf][nf][r];
        if (EPI == 0) {
          oB[rb + col] = f2bf(v * scale);
        } else if (EPI == 1) {
          oF[rb + col] = v + rs[rb + col];
        } else if (EPI == 2) {
          oB[rb + col] = f2bf(fast_gelu(v + bcol[nf]));
        } else {
          oF[rb + col] = v + bcol[nf] + rs[rb + col];
        }
      }
    }
  }
}

// ---------- LayerNorm over rows of 1024 fp32 -> bf16 ----------
__global__ __launch_bounds__(256) void ln_row(
    const float* __restrict__ x, const float* __restrict__ gamma,
    const float* __restrict__ beta, unsigned short* __restrict__ out)
{
  const int row = blockIdx.x;
  const float4* xr = (const float4*)(x + (size_t)row * 1024);
  const int tid = threadIdx.x;
  float4 v = xr[tid];
  float s = v.x + v.y + v.z + v.w;
  float q = v.x * v.x + v.y * v.y + v.z * v.z + v.w * v.w;
#pragma unroll
  for (int off = 32; off > 0; off >>= 1) {
    s += __shfl_down(s, off);
    q += __shfl_down(q, off);
  }
  __shared__ float rs_[4], rq_[4];
  const int w = tid >> 6, l = tid & 63;
  if (l == 0) { rs_[w] = s; rq_[w] = q; }
  __syncthreads();
  s = rs_[0] + rs_[1] + rs_[2] + rs_[3];
  q = rq_[0] + rq_[1] + rq_[2] + rq_[3];
  const float mu = s * (1.0f / 1024.0f);
  const float var = q * (1.0f / 1024.0f) - mu * mu;
  const float rstd = rsqrtf(var + 1e-5f);
  const float4 g = ((const float4*)gamma)[tid];
  const float4 b = ((const float4*)beta)[tid];
  us4 o;
  o.x = f2bf((v.x - mu) * rstd * g.x + b.x);
  o.y = f2bf((v.y - mu) * rstd * g.y + b.y);
  o.z = f2bf((v.z - mu) * rstd * g.z + b.z);
  o.w = f2bf((v.w - mu) * rstd * g.w + b.w);
  ((us4*)(out + (size_t)row * 1024))[tid] = o;
}

// ---------- softmax over rows of 2048 bf16 -> bf16 ----------
__global__ __launch_bounds__(256) void softmax_row(
    const unsigned short* __restrict__ sc, unsigned short* __restrict__ pr)
{
  const int row = blockIdx.x;
  const s8vec* s8 = (const s8vec*)(sc + (size_t)row * 2048);
  const int tid = threadIdx.x;
  s8vec a = s8[tid];                 // 8 bf16
  float x[8];
#pragma unroll
  for (int i = 0; i < 8; ++i) x[i] = bf2f((unsigned short)a[i]);
  float mx = x[0];
#pragma unroll
  for (int i = 1; i < 8; ++i) mx = fmaxf(mx, x[i]);
#pragma unroll
  for (int off = 32; off > 0; off >>= 1) mx = fmaxf(mx, __shfl_down(mx, off));
  __shared__ float red[4];
  const int w = tid >> 6, l = tid & 63;
  if (l == 0) red[w] = mx;
  __syncthreads();
  mx = fmaxf(fmaxf(red[0], red[1]), fmaxf(red[2], red[3]));
  __syncthreads();
  float e[8], s = 0.f;
#pragma unroll
  for (int i = 0; i < 8; ++i) { e[i] = __expf(x[i] - mx); s += e[i]; }
#pragma unroll
  for (int off = 32; off > 0; off >>= 1) s += __shfl_down(s, off);
  if (l == 0) red[w] = s;
  __syncthreads();
  s = red[0] + red[1] + red[2] + red[3];
  const float inv = 1.0f / s;
  s8vec o;
#pragma unroll
  for (int i = 0; i < 8; ++i) o[i] = (short)f2bf(e[i] * inv);
  ((s8vec*)(pr + (size_t)row * 2048))[tid] = o;
}

// ---------- fast 64x64-tile transposes (vectorized; G13) ----------
__global__ __launch_bounds__(256) void tconv_f32(
    const float* __restrict__ in, unsigned short* __restrict__ out, int R, int C)
{
  __shared__ float tile[64][65];
  const int tid = threadIdx.x;
  const int c0 = blockIdx.x * 64, r0 = blockIdx.y * 64;
#pragma unroll
  for (int k2 = 0; k2 < 4; ++k2) {
    const int idx = tid + k2 * 256;
    const int row = idx >> 4, c4 = (idx & 15) << 2;
    const float4 v = *(const float4*)&in[(size_t)(r0 + row) * C + c0 + c4];
    tile[row][c4] = v.x; tile[row][c4 + 1] = v.y;
    tile[row][c4 + 2] = v.z; tile[row][c4 + 3] = v.w;
  }
  __syncthreads();
#pragma unroll
  for (int k2 = 0; k2 < 4; ++k2) {
    const int idx = tid + k2 * 256;
    const int cc = idx >> 4, r4 = (idx & 15) << 2;
    us4 o;
#pragma unroll
    for (int j = 0; j < 4; ++j) o[j] = f2bf(tile[r4 + j][cc]);
    *(us4*)&out[(size_t)(c0 + cc) * R + r0 + r4] = o;
  }
}

__global__ __launch_bounds__(256) void tconv_bf16(
    const unsigned short* __restrict__ in, unsigned short* __restrict__ out,
    int R, int C, long long bIn, long long bOut)
{
  __shared__ unsigned short tile[64][66];
  const int tid = threadIdx.x;
  const int z = blockIdx.z;
  in += (size_t)z * bIn;
  out += (size_t)z * bOut;
  const int c0 = blockIdx.x * 64, r0 = blockIdx.y * 64;
#pragma unroll
  for (int k2 = 0; k2 < 2; ++k2) {
    const int idx = tid + k2 * 256;
    const int row = idx >> 3, c8 = (idx & 7) << 3;
    const us8 v = *(const us8*)&in[(size_t)(r0 + row) * C + c0 + c8];
#pragma unroll
    for (int j = 0; j < 8; ++j) tile[row][c8 + j] = v[j];
  }
  __syncthreads();
#pragma unroll
  for (int k2 = 0; k2 < 4; ++k2) {
    const int idx = tid + k2 * 256;
    const int cc = idx >> 4, r4 = (idx & 15) << 2;
    us4 o;
#pragma unroll
    for (int j = 0; j < 4; ++j) o[j] = tile[r4 + j][cc];
    *(us4*)&out[(size_t)(c0 + cc) * R + r0 + r4] = o;
  }
}

// ---------- launch ----------
extern "C" void kernel_launch(void* const* d_in, const int* in_sizes, int n_in,
                              void* d_out, int out_size, void* d_ws, size_t ws_size,
                              hipStream_t stream)
{
  (void)in_sizes; (void)n_in; (void)out_size; (void)ws_size;
  const float* src = (const float*)d_in[0];
  const float* g1  = (const float*)d_in[1];
  const float* be1 = (const float*)d_in[2];
  const float* g2  = (const float*)d_in[3];
  const float* be2 = (const float*)d_in[4];
  const float* w1  = (const float*)d_in[5];
  const float* b1  = (const float*)d_in[6];
  const float* w2  = (const float*)d_in[7];
  const float* b2  = (const float*)d_in[8];
  float* out = (float*)d_out;

  // workspace layout (bytes). Peak = 184,549,376.
  char* ws = (char*)d_ws;
  const size_t SZ_NORMX  = (size_t)8192 * 1024 * 2;     // 16 MiB
  const size_t SZ_SCORES = (size_t)4 * 2048 * 2048 * 4; // 64 MiB region
  const size_t SZ_PROBS  = (size_t)4 * 2048 * 2048 * 2; // 32 MiB
  const size_t SZ_X      = (size_t)8192 * 1024 * 4;     // 32 MiB
  const size_t SZ_W1T    = (size_t)1024 * 4096 * 2;     // 8 MiB

  unsigned short* normx  = (unsigned short*)(ws);
  unsigned short* normxT = (unsigned short*)(ws + SZ_NORMX);
  unsigned short* scores = (unsigned short*)(ws + 2 * SZ_NORMX);
  unsigned short* probs  = (unsigned short*)(ws + 2 * SZ_NORMX + SZ_SCORES);
  float*          xbuf   = (float*)(ws + 2 * SZ_NORMX + SZ_SCORES + SZ_PROBS);
  unsigned short* w1t    = (unsigned short*)(ws + 2 * SZ_NORMX + SZ_SCORES + SZ_PROBS + SZ_X);
  unsigned short* w2t    = (unsigned short*)(ws + 2 * SZ_NORMX + SZ_SCORES + SZ_PROBS + SZ_X + SZ_W1T);
  unsigned short* normx2 = normx;                       // reuse (dead after attn)
  unsigned short* hbuf   = scores;                      // reuse (dead after softmax)

  // weights fp32 -> bf16 transposed (every call; ws is re-poisoned)
  tconv_f32<<<dim3(64, 16), 256, 0, stream>>>(w1, w1t, 1024, 4096);
  tconv_f32<<<dim3(16, 64), 256, 0, stream>>>(w2, w2t, 4096, 1024);

  // LN1
  ln_row<<<8192, 256, 0, stream>>>(src, g1, be1, normx);
  // normx^T per batch (for PV as NT)
  tconv_bf16<<<dim3(16, 32, 4), 256, 0, stream>>>(
      normx, normxT, 2048, 1024, (long long)2048 * 1024, (long long)1024 * 2048);

  // scores = bf16(normx . normx^T / 32)      [2-blocks/CU experiment kernel]
  gemm2b<0><<<dim3(16, 16, 4), 512, 0, stream>>>(
      normx, normx, nullptr, scores, nullptr, nullptr,
      2048, 2048, 1024,
      (long long)2048 * 1024, (long long)2048 * 1024, (long long)2048 * 2048, 0, 0.03125f);

  // softmax rows (bf16 in/out)
  softmax_row<<<8192, 256, 0, stream>>>(scores, probs);

  // x = probs . normx + src                   [round-4 path, measured best]
  gemm_nt8<128, 1><<<dim3(8, 8, 4), 512, 0, stream>>>(
      probs, normxT, xbuf, nullptr, nullptr, src,
      2048, 1024, 2048,
      (long long)2048 * 2048, (long long)1024 * 2048, (long long)2048 * 1024,
      (long long)2048 * 1024, 1.0f);

  // LN2
  ln_row<<<8192, 256, 0, stream>>>(xbuf, g2, be2, normx2);

  // h = gelu(normx2 . w1 + b1)                [2-blocks/CU experiment kernel]
  gemm2b<2><<<dim3(32, 64, 1), 512, 0, stream>>>(
      normx2, w1t, nullptr, hbuf, b1, nullptr,
      8192, 4096, 1024, 0, 0, 0, 0, 1.0f);

  // out = h . w2 + b2 + x                     [round-4 path, measured best]
  gemm_nt8<128, 3><<<dim3(8, 32, 1), 512, 0, stream>>>(
      hbuf, w2t, out, nullptr, b2, xbuf,
      8192, 1024, 4096, 0, 0, 0, 0, 1.0f);
}

// Round 9
// 397.189 us; speedup vs baseline: 1.0464x; 1.0464x over previous
//
#include <hip/hip_runtime.h>
#include <hip/hip_bf16.h>
#include <math.h>

// ---------- types ----------
typedef __attribute__((ext_vector_type(8))) short s8vec;     // 8 x bf16 bits (4 VGPRs)
typedef __attribute__((ext_vector_type(16))) float f32x16;   // 32x32 MFMA C/D
typedef __attribute__((ext_vector_type(4))) unsigned short us4;
typedef __attribute__((ext_vector_type(8))) unsigned short us8;
typedef long long i64frag;                                   // 8 x fp8 (2 VGPRs)

__device__ __forceinline__ unsigned short f2bf(float f) {
  unsigned u = __float_as_uint(f);
  u = (u + 0x7fffu + ((u >> 16) & 1u)) >> 16;   // RNE
  return (unsigned short)u;
}
__device__ __forceinline__ float bf2f(unsigned short u) {
  return __uint_as_float(((unsigned)u) << 16);
}

// float -> OCP e4m3fn, RNE; clamps to +-448; subnormals quantized at 2^-9.
__device__ __forceinline__ unsigned char f2e4m3(float f) {
  unsigned u = __float_as_uint(f);
  unsigned s = (u >> 24) & 0x80u;
  float a = __uint_as_float(u & 0x7FFFFFFFu);
  a = fminf(a, 448.0f);
  unsigned char m;
  if (a < 0.015625f) {                       // e4m3 subnormal range
    m = (unsigned char)__float2int_rn(a * 512.0f);   // step 2^-9 (8 -> min normal, still valid)
  } else {
    unsigned x = __float_as_uint(a);
    x += 0x0007FFFFu + ((x >> 20) & 1u);     // RNE to 3-bit mantissa
    int e = (int)(x >> 23) - 120;            // e4m3 bias 7
    if (e >= 16) m = 0x7E;                   // clamp (unreachable after fminf)
    else m = (unsigned char)((e << 3) | ((x >> 20) & 7u));
  }
  return (unsigned char)(s | m);
}

// fast gelu: t * sigmoid(1.5957691t + 0.07135481t^3); |err vs erf-gelu| < 3e-3
__device__ __forceinline__ float fast_gelu(float t) {
  float t2 = t * t;
  float u = t * (1.59576912f + 0.07135481f * t2);
  float e = __expf(-u);
  return t * __frcp_rn(1.0f + e);
}

// async global->LDS, 16B per lane. LDS dest = wave-uniform base + lane*16. offset always 0.
__device__ __forceinline__ void async_ld16(const unsigned short* g, unsigned short* l) {
  __builtin_amdgcn_global_load_lds(
      (__attribute__((address_space(1))) void*)g,
      (__attribute__((address_space(3))) void*)l, 16, 0, 0);
}
__device__ __forceinline__ void async_ld16b(const unsigned char* g, unsigned char* l) {
  __builtin_amdgcn_global_load_lds(
      (__attribute__((address_space(1))) void*)g,
      (__attribute__((address_space(3))) void*)l, 16, 0, 0);
}

#define SB0() __builtin_amdgcn_sched_barrier(0)

// ============================================================================
// Round-4 256xBN NT GEMM (measured best bf16 path) — scores/PV/FFN2.
// ============================================================================

#define STA(q, tk, bofs)                                                    \
  async_ld16(srcA0 + (size_t)(q) * 32 * K + ((size_t)(tk) << 6),            \
             &As[(bofs) + ldsA0 + (q) * 2048])
#define STB(j, tk, bofs)                                                    \
  async_ld16(srcB0 + (size_t)(j) * 64 * K + ((size_t)(tk) << 6),            \
             &Bs[(bofs) + ldsB0 + (j) * 4096])

template <int BN, int EPI>
__global__ __launch_bounds__(512, 2) void gemm_nt8(
    const unsigned short* __restrict__ A, const unsigned short* __restrict__ B,
    float* __restrict__ outF, unsigned short* __restrict__ outB,
    const float* __restrict__ bias, const float* __restrict__ res,
    int M, int N, int K,
    long long bA, long long bB, long long bO, long long bR, float scale)
{
  static_assert(BN == 256 || BN == 128, "BN must be 256 or 128");
  constexpr int NB = BN / 64;
  constexpr int NF = BN / 128;
  constexpr int WN = BN / 4;
  constexpr int ABUF = 256 * 64;
  constexpr int BBUF = BN * 64;

  __shared__ __align__(16) unsigned short As[2 * ABUF];
  __shared__ __align__(16) unsigned short Bs[2 * BBUF];

  (void)M;
  const int tid = threadIdx.x;
  const int w = tid >> 6;
  const int l = tid & 63;

  const unsigned gx = gridDim.x, gy = gridDim.y;
  unsigned lin = blockIdx.x + gx * (blockIdx.y + gy * blockIdx.z);
  const unsigned nwg = gx * gy * gridDim.z;
  lin = (lin & 7u) * (nwg >> 3) + (lin >> 3);
  const unsigned bx = lin & (gx - 1u);
  const unsigned tmp = lin >> __builtin_ctz(gx);
  const unsigned by = tmp & (gy - 1u);
  const unsigned bz = tmp >> __builtin_ctz(gy);

  const int z = (int)bz;
  A += (size_t)z * bA;
  B += (size_t)z * bB;
  const size_t tileM = (size_t)by * 256;
  const size_t tileN = (size_t)bx * BN;

  const int sub = w & 3, half = w >> 2;
  const int rA = sub * 8 + half * 128 + (l >> 3);
  const int cA = (l & 7) ^ (rA & 7) ^ ((rA >> 3) & 3);
  const unsigned short* srcA0 = A + (tileM + rA) * (size_t)K + (cA << 3);
  const int ldsA0 = (sub * 8 + half * 128) * 64;

  const int rB = w * 8 + (l >> 3);
  const int cB = (l & 7) ^ (rB & 7) ^ ((rB >> 3) & 3);
  const unsigned short* srcB0 = B + (tileN + rB) * (size_t)K + (cB << 3);
  const int ldsB0 = (w * 8) * 64;

  const int wm = half;
  const int wn = sub;
  const int fr = l & 31;
  const int fq = l >> 5;
  const int swz = (l & 7) ^ ((l >> 3) & 3);
  int pc[4];
#pragma unroll
  for (int s = 0; s < 4; ++s) pc[s] = ((((s << 1) + fq) ^ swz) << 3);
  const int aoff = (wm * 128 + fr) * 64;
  int boff[NF];
#pragma unroll
  for (int nf = 0; nf < NF; ++nf) boff[nf] = (wn * WN + nf * 32 + fr) * 64;

  f32x16 acc[4][NF] = {};
  const int NT = K >> 6;

  STA(0, 0, 0); STA(1, 0, 0); STA(2, 0, 0); STA(3, 0, 0);
#pragma unroll
  for (int j = 0; j < NB; ++j) STB(j, 0, 0);
#pragma unroll
  for (int j = 0; j < NB; ++j) STB(j, 1, BBUF);
  STA(0, 1, ABUF); STA(1, 1, ABUF);
  if constexpr (NB == 4) asm volatile("s_waitcnt vmcnt(6)" ::: "memory");
  else                   asm volatile("s_waitcnt vmcnt(4)" ::: "memory");
  __builtin_amdgcn_s_barrier();

  auto tile = [&](int t, int bf) {
    const int aB = bf * ABUF, bBo = bf * BBUF, oaB = (bf ^ 1) * ABUF;
    const bool g1 = (t + 1 < NT), g2 = (t + 2 < NT);
    s8vec b[NF][4], aA[2][4], aC[2][4];

#pragma unroll
    for (int s = 0; s < 4; ++s) {
#pragma unroll
      for (int nf = 0; nf < NF; ++nf)
        b[nf][s] = *(const s8vec*)&Bs[bBo + boff[nf] + pc[s]];
      aA[0][s] = *(const s8vec*)&As[aB + aoff + 0 * 2048 + pc[s]];
      aA[1][s] = *(const s8vec*)&As[aB + aoff + 1 * 2048 + pc[s]];
    }
    SB0();
#pragma unroll
    for (int s = 0; s < 4; ++s) {
      aC[0][s] = *(const s8vec*)&As[aB + aoff + 2 * 2048 + pc[s]];
      aC[1][s] = *(const s8vec*)&As[aB + aoff + 3 * 2048 + pc[s]];
    }
    if (g1) { STA(2, t + 1, oaB); STA(3, t + 1, oaB); }
    SB0();
    asm volatile("s_waitcnt lgkmcnt(8)" ::: "memory");
    SB0();
    __builtin_amdgcn_s_setprio(1);
#pragma unroll
    for (int s = 0; s < 4; ++s)
#pragma unroll
      for (int i = 0; i < 2; ++i)
#pragma unroll
        for (int nf = 0; nf < NF; ++nf)
          acc[i][nf] = __builtin_amdgcn_mfma_f32_32x32x16_bf16(aA[i][s], b[nf][s], acc[i][nf], 0, 0, 0);
    SB0();
    __builtin_amdgcn_s_setprio(0);
    __builtin_amdgcn_s_barrier();

    if (g2) {
#pragma unroll
      for (int j = 0; j < NB; ++j) STB(j, t + 2, bBo);
      STA(0, t + 2, aB); STA(1, t + 2, aB);
    }
    SB0();
    asm volatile("s_waitcnt lgkmcnt(0)" ::: "memory");
    SB0();
    __builtin_amdgcn_s_setprio(1);
#pragma unroll
    for (int s = 0; s < 4; ++s)
#pragma unroll
      for (int i = 0; i < 2; ++i)
#pragma unroll
        for (int nf = 0; nf < NF; ++nf)
          acc[2 + i][nf] = __builtin_amdgcn_mfma_f32_32x32x16_bf16(aC[i][s], b[nf][s], acc[2 + i][nf], 0, 0, 0);
    SB0();
    __builtin_amdgcn_s_setprio(0);
    if (g2) {
      if constexpr (NB == 4) asm volatile("s_waitcnt vmcnt(6)" ::: "memory");
      else                   asm volatile("s_waitcnt vmcnt(4)" ::: "memory");
    } else {
      asm volatile("s_waitcnt vmcnt(0)" ::: "memory");
    }
    __builtin_amdgcn_s_barrier();
  };

  for (int t = 0; t < NT; t += 2) { tile(t, 0); tile(t + 1, 1); }

  float* oF = outF + (size_t)z * bO;
  unsigned short* oB = outB + (size_t)z * bO;
  const float* rs = res + (size_t)z * bR;

  float bcol[NF];
  if (EPI >= 2) {
#pragma unroll
    for (int nf = 0; nf < NF; ++nf) bcol[nf] = bias[tileN + wn * WN + nf * 32 + fr];
  }

#pragma unroll
  for (int mf = 0; mf < 4; ++mf) {
#pragma unroll
    for (int r = 0; r < 16; ++r) {
      const size_t row = tileM + wm * 128 + (mf << 5) + (r & 3) + ((r >> 2) << 3) + (fq << 2);
      const size_t rb = row * (size_t)N;
#pragma unroll
      for (int nf = 0; nf < NF; ++nf) {
        const size_t col = tileN + wn * WN + (nf << 5) + fr;
        const float v = acc[mf][nf][r];
        if (EPI == 0) {
          oB[rb + col] = f2bf(v * scale);
        } else if (EPI == 1) {
          oF[rb + col] = v + rs[rb + col];
        } else if (EPI == 2) {
          oB[rb + col] = f2bf(fast_gelu(v + bcol[nf]));
        } else {
          oF[rb + col] = v + bcol[nf] + rs[rb + col];
        }
      }
    }
  }
}

// ============================================================================
// gemm_fp8: 256x256 NT GEMM in fp8-e4m3, BK=128 — FFN1 only.
// out_bf16 = gelu(acc*scale + bias).  Structure = round-4 gemm_nt8<256>
// verbatim (same stripe geometry, same 8-issue/tile ledger, same vmcnt(6)
// boundary, same 8-chunk XOR swizzle — BYTE-identical layout since a
// 128-fp8 row == 128 B == a 64-bf16 row).  8 K-tiles instead of 16:
// half the barriers, half the ds_read bytes, half the A/B HBM fetch.
// Frag = 8 fp8 = i64; k = (l>>5)*8 + e (byte-analog of the proven bf16
// mapping); reads are ds_read_b64 at byte ((p^swz)<<4) + (fq<<3).
// Windows: WA batch1 = B(16)+A-mf01(16) reads, batch2 = A-mf23(16);
// lgkm(12) guarantees batch1 done (48 issued, <=12 left => >=36 retired);
// 32 MFMA; barrier.  WB: stage B0-3+A01(t+2); lgkm(0); 32 MFMA; vmcnt(6).
// ============================================================================

#define F8STA(q, tk, bofs)                                                  \
  async_ld16b(srcA0 + (size_t)(q) * 32 * K + (size_t)(tk) * 128,            \
              &As8[(bofs) + ldsA0 + (q) * 4096])
#define F8STB(j, tk, bofs)                                                  \
  async_ld16b(srcB0 + (size_t)(j) * 64 * K + (size_t)(tk) * 128,            \
              &Bs8[(bofs) + ldsB0 + (j) * 8192])

__global__ __launch_bounds__(512, 2) void gemm_fp8(
    const unsigned char* __restrict__ A, const unsigned char* __restrict__ B,
    unsigned short* __restrict__ outB, const float* __restrict__ bias,
    int N, int K, float scale)
{
  constexpr int ABUF8 = 256 * 128;   // 32 KiB per buffer
  constexpr int BBUF8 = 256 * 128;
  __shared__ __align__(16) unsigned char As8[2 * ABUF8];   // 64 KiB
  __shared__ __align__(16) unsigned char Bs8[2 * BBUF8];   // 64 KiB

  const int tid = threadIdx.x;
  const int w = tid >> 6;
  const int l = tid & 63;

  // T1 remap (gx=16 pow2, nwg=512 % 8 == 0)
  const unsigned gx = gridDim.x, gy = gridDim.y;
  unsigned lin = blockIdx.x + gx * blockIdx.y;
  const unsigned nwg = gx * gy;
  lin = (lin & 7u) * (nwg >> 3) + (lin >> 3);
  const unsigned bx = lin & (gx - 1u);
  const unsigned by = lin >> __builtin_ctz(gx);

  const size_t tileM = (size_t)by * 256;
  const size_t tileN = (size_t)bx * 256;

  // staging bases (global pre-swizzled in 16B chunks, LDS linear)
  const int sub = w & 3, half = w >> 2;
  const int rA = sub * 8 + half * 128 + (l >> 3);
  const int cA = (l & 7) ^ (rA & 7) ^ ((rA >> 3) & 3);
  const unsigned char* srcA0 = A + (tileM + rA) * (size_t)K + (cA << 4);
  const int ldsA0 = (sub * 8 + half * 128) * 128;

  const int rB = w * 8 + (l >> 3);
  const int cB = (l & 7) ^ (rB & 7) ^ ((rB >> 3) & 3);
  const unsigned char* srcB0 = B + (tileN + rB) * (size_t)K + (cB << 4);
  const int ldsB0 = (w * 8) * 128;

  // compute-side addressing
  const int wm = half, wn = sub;
  const int fr = l & 31;
  const int fq = l >> 5;
  const int swz = (l & 7) ^ ((l >> 3) & 3);
  int pr[8];
#pragma unroll
  for (int p = 0; p < 8; ++p) pr[p] = ((p ^ swz) << 4) + (fq << 3);
  const int aoffB = (wm * 128 + fr) * 128;              // + mf*4096
  int boffB[2];
#pragma unroll
  for (int nf = 0; nf < 2; ++nf) boffB[nf] = (wn * 64 + nf * 32 + fr) * 128;

  f32x16 acc[4][2] = {};
  const int NT = K >> 7;            // 128-K tiles (K=1024 -> 8, even)

  // prologue: t0 full (8 oldest), t1 B(4)+A01(2); vmcnt(6) -> t0 resident
  F8STA(0, 0, 0); F8STA(1, 0, 0); F8STA(2, 0, 0); F8STA(3, 0, 0);
#pragma unroll
  for (int j = 0; j < 4; ++j) F8STB(j, 0, 0);
#pragma unroll
  for (int j = 0; j < 4; ++j) F8STB(j, 1, BBUF8);
  F8STA(0, 1, ABUF8); F8STA(1, 1, ABUF8);
  asm volatile("s_waitcnt vmcnt(6)" ::: "memory");
  __builtin_amdgcn_s_barrier();

  auto tile = [&](int t, int bf) {
    const int aB = bf * ABUF8, bBo = bf * BBUF8, oaB = (bf ^ 1) * ABUF8;
    const bool g1 = (t + 1 < NT), g2 = (t + 2 < NT);
    i64frag b[2][8], aA[2][8], aC[2][8];

    // -- WA: batch1 (B + A-mf01, 32 reads), batch2 (A-mf23, 16 reads);
    //        stage A23(t+1, other buf) --
#pragma unroll
    for (int s = 0; s < 8; ++s) {
      b[0][s]  = *(const i64frag*)&Bs8[bBo + boffB[0] + pr[s]];
      b[1][s]  = *(const i64frag*)&Bs8[bBo + boffB[1] + pr[s]];
      aA[0][s] = *(const i64frag*)&As8[aB + aoffB + 0 * 4096 + pr[s]];
      aA[1][s] = *(const i64frag*)&As8[aB + aoffB + 1 * 4096 + pr[s]];
    }
    SB0();                          // pin batch boundary: (b,aA) | (aC)
#pragma unroll
    for (int s = 0; s < 8; ++s) {
      aC[0][s] = *(const i64frag*)&As8[aB + aoffB + 2 * 4096 + pr[s]];
      aC[1][s] = *(const i64frag*)&As8[aB + aoffB + 3 * 4096 + pr[s]];
    }
    if (g1) { F8STA(2, t + 1, oaB); F8STA(3, t + 1, oaB); }
    SB0();
    asm volatile("s_waitcnt lgkmcnt(12)" ::: "memory");   // batch1 (32) done
    SB0();
    __builtin_amdgcn_s_setprio(1);
#pragma unroll
    for (int s = 0; s < 8; ++s)
#pragma unroll
      for (int i = 0; i < 2; ++i)
#pragma unroll
        for (int nf = 0; nf < 2; ++nf)
          acc[i][nf] = __builtin_amdgcn_mfma_f32_32x32x16_fp8_fp8(
              aA[i][s], b[nf][s], acc[i][nf], 0, 0, 0);
    SB0();
    __builtin_amdgcn_s_setprio(0);
    __builtin_amdgcn_s_barrier();   // all waves past lgkm(12): B/A01 restageable

    // -- WB: stage B0-3 + A01 (t+2, this buf); MFMA mf23; boundary vmcnt --
    if (g2) {
#pragma unroll
      for (int j = 0; j < 4; ++j) F8STB(j, t + 2, bBo);
      F8STA(0, t + 2, aB); F8STA(1, t + 2, aB);
    }
    SB0();
    asm volatile("s_waitcnt lgkmcnt(0)" ::: "memory");    // batch2 done
    SB0();
    __builtin_amdgcn_s_setprio(1);
#pragma unroll
    for (int s = 0; s < 8; ++s)
#pragma unroll
      for (int i = 0; i < 2; ++i)
#pragma unroll
        for (int nf = 0; nf < 2; ++nf)
          acc[2 + i][nf] = __builtin_amdgcn_mfma_f32_32x32x16_fp8_fp8(
              aC[i][s], b[nf][s], acc[2 + i][nf], 0, 0, 0);
    SB0();
    __builtin_amdgcn_s_setprio(0);
    if (g2) asm volatile("s_waitcnt vmcnt(6)" ::: "memory");
    else    asm volatile("s_waitcnt vmcnt(0)" ::: "memory");
    __builtin_amdgcn_s_barrier();
  };

  for (int t = 0; t < NT; t += 2) { tile(t, 0); tile(t + 1, 1); }

  // epilogue: out = bf16(gelu(acc*scale + bias))
  float bcol[2];
#pragma unroll
  for (int nf = 0; nf < 2; ++nf) bcol[nf] = bias[tileN + wn * 64 + nf * 32 + fr];

#pragma unroll
  for (int mf = 0; mf < 4; ++mf) {
#pragma unroll
    for (int r = 0; r < 16; ++r) {
      const size_t row = tileM + wm * 128 + (mf << 5) + (r & 3) + ((r >> 2) << 3) + (fq << 2);
      const size_t rb = row * (size_t)N;
#pragma unroll
      for (int nf = 0; nf < 2; ++nf) {
        const size_t col = tileN + wn * 64 + (nf << 5) + fr;
        outB[rb + col] = f2bf(fast_gelu(acc[mf][nf][r] * scale + bcol[nf]));
      }
    }
  }
}

// ---------- LayerNorm over rows of 1024 fp32 -> bf16 ----------
__global__ __launch_bounds__(256) void ln_row(
    const float* __restrict__ x, const float* __restrict__ gamma,
    const float* __restrict__ beta, unsigned short* __restrict__ out)
{
  const int row = blockIdx.x;
  const float4* xr = (const float4*)(x + (size_t)row * 1024);
  const int tid = threadIdx.x;
  float4 v = xr[tid];
  float s = v.x + v.y + v.z + v.w;
  float q = v.x * v.x + v.y * v.y + v.z * v.z + v.w * v.w;
#pragma unroll
  for (int off = 32; off > 0; off >>= 1) {
    s += __shfl_down(s, off);
    q += __shfl_down(q, off);
  }
  __shared__ float rs_[4], rq_[4];
  const int w = tid >> 6, l = tid & 63;
  if (l == 0) { rs_[w] = s; rq_[w] = q; }
  __syncthreads();
  s = rs_[0] + rs_[1] + rs_[2] + rs_[3];
  q = rq_[0] + rq_[1] + rq_[2] + rq_[3];
  const float mu = s * (1.0f / 1024.0f);
  const float var = q * (1.0f / 1024.0f) - mu * mu;
  const float rstd = rsqrtf(var + 1e-5f);
  const float4 g = ((const float4*)gamma)[tid];
  const float4 b = ((const float4*)beta)[tid];
  us4 o;
  o.x = f2bf((v.x - mu) * rstd * g.x + b.x);
  o.y = f2bf((v.y - mu) * rstd * g.y + b.y);
  o.z = f2bf((v.z - mu) * rstd * g.z + b.z);
  o.w = f2bf((v.w - mu) * rstd * g.w + b.w);
  ((us4*)(out + (size_t)row * 1024))[tid] = o;
}

// ---------- LayerNorm over rows of 1024 fp32 -> fp8 e4m3 ----------
__global__ __launch_bounds__(256) void ln_row_fp8(
    const float* __restrict__ x, const float* __restrict__ gamma,
    const float* __restrict__ beta, unsigned char* __restrict__ out)
{
  const int row = blockIdx.x;
  const float4* xr = (const float4*)(x + (size_t)row * 1024);
  const int tid = threadIdx.x;
  float4 v = xr[tid];
  float s = v.x + v.y + v.z + v.w;
  float q = v.x * v.x + v.y * v.y + v.z * v.z + v.w * v.w;
#pragma unroll
  for (int off = 32; off > 0; off >>= 1) {
    s += __shfl_down(s, off);
    q += __shfl_down(q, off);
  }
  __shared__ float rs_[4], rq_[4];
  const int w = tid >> 6, l = tid & 63;
  if (l == 0) { rs_[w] = s; rq_[w] = q; }
  __syncthreads();
  s = rs_[0] + rs_[1] + rs_[2] + rs_[3];
  q = rq_[0] + rq_[1] + rq_[2] + rq_[3];
  const float mu = s * (1.0f / 1024.0f);
  const float var = q * (1.0f / 1024.0f) - mu * mu;
  const float rstd = rsqrtf(var + 1e-5f);
  const float4 g = ((const float4*)gamma)[tid];
  const float4 b = ((const float4*)beta)[tid];
  unsigned pack =  (unsigned)f2e4m3((v.x - mu) * rstd * g.x + b.x)
                | ((unsigned)f2e4m3((v.y - mu) * rstd * g.y + b.y) << 8)
                | ((unsigned)f2e4m3((v.z - mu) * rstd * g.z + b.z) << 16)
                | ((unsigned)f2e4m3((v.w - mu) * rstd * g.w + b.w) << 24);
  ((unsigned*)(out + (size_t)row * 1024))[tid] = pack;
}

// ---------- softmax over rows of 2048 bf16 -> bf16 ----------
__global__ __launch_bounds__(256) void softmax_row(
    const unsigned short* __restrict__ sc, unsigned short* __restrict__ pr)
{
  const int row = blockIdx.x;
  const s8vec* s8 = (const s8vec*)(sc + (size_t)row * 2048);
  const int tid = threadIdx.x;
  s8vec a = s8[tid];                 // 8 bf16
  float x[8];
#pragma unroll
  for (int i = 0; i < 8; ++i) x[i] = bf2f((unsigned short)a[i]);
  float mx = x[0];
#pragma unroll
  for (int i = 1; i < 8; ++i) mx = fmaxf(mx, x[i]);
#pragma unroll
  for (int off = 32; off > 0; off >>= 1) mx = fmaxf(mx, __shfl_down(mx, off));
  __shared__ float red[4];
  const int w = tid >> 6, l = tid & 63;
  if (l == 0) red[w] = mx;
  __syncthreads();
  mx = fmaxf(fmaxf(red[0], red[1]), fmaxf(red[2], red[3]));
  __syncthreads();
  float e[8], s = 0.f;
#pragma unroll
  for (int i = 0; i < 8; ++i) { e[i] = __expf(x[i] - mx); s += e[i]; }
#pragma unroll
  for (int off = 32; off > 0; off >>= 1) s += __shfl_down(s, off);
  if (l == 0) red[w] = s;
  __syncthreads();
  s = red[0] + red[1] + red[2] + red[3];
  const float inv = 1.0f / s;
  s8vec o;
#pragma unroll
  for (int i = 0; i < 8; ++i) o[i] = (short)f2bf(e[i] * inv);
  ((s8vec*)(pr + (size_t)row * 2048))[tid] = o;
}

// ---------- fast 64x64-tile transposes (vectorized; G13) ----------
// f32 in [R][C] -> bf16 out [C][R]
__global__ __launch_bounds__(256) void tconv_f32(
    const float* __restrict__ in, unsigned short* __restrict__ out, int R, int C)
{
  __shared__ float tile[64][65];
  const int tid = threadIdx.x;
  const int c0 = blockIdx.x * 64, r0 = blockIdx.y * 64;
#pragma unroll
  for (int k2 = 0; k2 < 4; ++k2) {
    const int idx = tid + k2 * 256;
    const int row = idx >> 4, c4 = (idx & 15) << 2;
    const float4 v = *(const float4*)&in[(size_t)(r0 + row) * C + c0 + c4];
    tile[row][c4] = v.x; tile[row][c4 + 1] = v.y;
    tile[row][c4 + 2] = v.z; tile[row][c4 + 3] = v.w;
  }
  __syncthreads();
#pragma unroll
  for (int k2 = 0; k2 < 4; ++k2) {
    const int idx = tid + k2 * 256;
    const int cc = idx >> 4, r4 = (idx & 15) << 2;
    us4 o;
#pragma unroll
    for (int j = 0; j < 4; ++j) o[j] = f2bf(tile[r4 + j][cc]);
    *(us4*)&out[(size_t)(c0 + cc) * R + r0 + r4] = o;
  }
}

// f32 in [R][C] -> fp8 out [C][R], value scaled by SC (for w1: SC=16)
__global__ __launch_bounds__(256) void tconv_f32_fp8(
    const float* __restrict__ in, unsigned char* __restrict__ out,
    int R, int C, float SC)
{
  __shared__ float tile[64][65];
  const int tid = threadIdx.x;
  const int c0 = blockIdx.x * 64, r0 = blockIdx.y * 64;
#pragma unroll
  for (int k2 = 0; k2 < 4; ++k2) {
    const int idx = tid + k2 * 256;
    const int row = idx >> 4, c4 = (idx & 15) << 2;
    const float4 v = *(const float4*)&in[(size_t)(r0 + row) * C + c0 + c4];
    tile[row][c4] = v.x; tile[row][c4 + 1] = v.y;
    tile[row][c4 + 2] = v.z; tile[row][c4 + 3] = v.w;
  }
  __syncthreads();
#pragma unroll
  for (int k2 = 0; k2 < 4; ++k2) {
    const int idx = tid + k2 * 256;
    const int cc = idx >> 4, r4 = (idx & 15) << 2;
    unsigned pack =  (unsigned)f2e4m3(tile[r4 + 0][cc] * SC)
                  | ((unsigned)f2e4m3(tile[r4 + 1][cc] * SC) << 8)
                  | ((unsigned)f2e4m3(tile[r4 + 2][cc] * SC) << 16)
                  | ((unsigned)f2e4m3(tile[r4 + 3][cc] * SC) << 24);
    *(unsigned*)&out[(size_t)(c0 + cc) * R + r0 + r4] = pack;
  }
}

// bf16 in [R][C] -> bf16 out [C][R], batched
__global__ __launch_bounds__(256) void tconv_bf16(
    const unsigned short* __restrict__ in, unsigned short* __restrict__ out,
    int R, int C, long long bIn, long long bOut)
{
  __shared__ unsigned short tile[64][66];
  const int tid = threadIdx.x;
  const int z = blockIdx.z;
  in += (size_t)z * bIn;
  out += (size_t)z * bOut;
  const int c0 = blockIdx.x * 64, r0 = blockIdx.y * 64;
#pragma unroll
  for (int k2 = 0; k2 < 2; ++k2) {
    const int idx = tid + k2 * 256;
    const int row = idx >> 3, c8 = (idx & 7) << 3;
    const us8 v = *(const us8*)&in[(size_t)(r0 + row) * C + c0 + c8];
#pragma unroll
    for (int j = 0; j < 8; ++j) tile[row][c8 + j] = v[j];
  }
  __syncthreads();
#pragma unroll
  for (int k2 = 0; k2 < 4; ++k2) {
    const int idx = tid + k2 * 256;
    const int cc = idx >> 4, r4 = (idx & 15) << 2;
    us4 o;
#pragma unroll
    for (int j = 0; j < 4; ++j) o[j] = tile[r4 + j][cc];
    *(us4*)&out[(size_t)(c0 + cc) * R + r0 + r4] = o;
  }
}

// ---------- launch ----------
extern "C" void kernel_launch(void* const* d_in, const int* in_sizes, int n_in,
                              void* d_out, int out_size, void* d_ws, size_t ws_size,
                              hipStream_t stream)
{
  (void)in_sizes; (void)n_in; (void)out_size; (void)ws_size;
  const float* src = (const float*)d_in[0];
  const float* g1  = (const float*)d_in[1];
  const float* be1 = (const float*)d_in[2];
  const float* g2  = (const float*)d_in[3];
  const float* be2 = (const float*)d_in[4];
  const float* w1  = (const float*)d_in[5];
  const float* b1  = (const float*)d_in[6];
  const float* w2  = (const float*)d_in[7];
  const float* b2  = (const float*)d_in[8];
  float* out = (float*)d_out;

  // workspace layout (bytes). Peak = 184,549,376.
  char* ws = (char*)d_ws;
  const size_t SZ_NORMX  = (size_t)8192 * 1024 * 2;     // 16 MiB
  const size_t SZ_SCORES = (size_t)4 * 2048 * 2048 * 4; // 64 MiB region
  const size_t SZ_PROBS  = (size_t)4 * 2048 * 2048 * 2; // 32 MiB
  const size_t SZ_X      = (size_t)8192 * 1024 * 4;     // 32 MiB
  const size_t SZ_W1T    = (size_t)1024 * 4096 * 2;     // 8 MiB

  unsigned short* normx  = (unsigned short*)(ws);
  unsigned short* normxT = (unsigned short*)(ws + SZ_NORMX);
  unsigned short* scores = (unsigned short*)(ws + 2 * SZ_NORMX);
  unsigned short* probs  = (unsigned short*)(ws + 2 * SZ_NORMX + SZ_SCORES);
  float*          xbuf   = (float*)(ws + 2 * SZ_NORMX + SZ_SCORES + SZ_PROBS);
  unsigned short* w1t    = (unsigned short*)(ws + 2 * SZ_NORMX + SZ_SCORES + SZ_PROBS + SZ_X);
  unsigned short* w2t    = (unsigned short*)(ws + 2 * SZ_NORMX + SZ_SCORES + SZ_PROBS + SZ_X + SZ_W1T);
  unsigned char*  normx28 = (unsigned char*)normx;      // fp8 LN2 out (normx dead after attn)
  unsigned char*  w1t8    = (unsigned char*)w1t;        // fp8 w1^T * 16 (4 MiB in 8 MiB slot)
  unsigned short* hbuf    = scores;                     // reuse (dead after softmax)

  // weights: w1 -> fp8 transposed (x16), w2 -> bf16 transposed
  tconv_f32_fp8<<<dim3(64, 16), 256, 0, stream>>>(w1, w1t8, 1024, 4096, 16.0f);
  tconv_f32<<<dim3(16, 64), 256, 0, stream>>>(w2, w2t, 4096, 1024);

  // LN1 (bf16)
  ln_row<<<8192, 256, 0, stream>>>(src, g1, be1, normx);
  // normx^T per batch (for PV as NT)
  tconv_bf16<<<dim3(16, 32, 4), 256, 0, stream>>>(
      normx, normxT, 2048, 1024, (long long)2048 * 1024, (long long)1024 * 2048);

  // scores = bf16(normx . normx^T / 32)      [round-4 bf16 path]
  gemm_nt8<256, 0><<<dim3(8, 8, 4), 512, 0, stream>>>(
      normx, normx, nullptr, scores, nullptr, nullptr,
      2048, 2048, 1024,
      (long long)2048 * 1024, (long long)2048 * 1024, (long long)2048 * 2048, 0, 0.03125f);

  // softmax rows (bf16 in/out)
  softmax_row<<<8192, 256, 0, stream>>>(scores, probs);

  // x = probs . normx + src                   [round-4 bf16 path]
  gemm_nt8<128, 1><<<dim3(8, 8, 4), 512, 0, stream>>>(
      probs, normxT, xbuf, nullptr, nullptr, src,
      2048, 1024, 2048,
      (long long)2048 * 2048, (long long)1024 * 2048, (long long)2048 * 1024,
      (long long)2048 * 1024, 1.0f);

  // LN2 -> fp8
  ln_row_fp8<<<8192, 256, 0, stream>>>(xbuf, g2, be2, normx28);

  // h = gelu((normx2_fp8 . (16*w1)_fp8)/16 + b1)   [fp8 experiment kernel]
  gemm_fp8<<<dim3(16, 32), 512, 0, stream>>>(
      normx28, w1t8, hbuf, b1, 4096, 1024, 0.0625f);

  // out = h . w2 + b2 + x                     [round-4 bf16 path]
  gemm_nt8<128, 3><<<dim3(8, 32, 1), 512, 0, stream>>>(
      hbuf, w2t, out, nullptr, b2, xbuf,
      8192, 1024, 4096, 0, 0, 0, 0, 1.0f);
}